// Round 5
// baseline (194.276 us; speedup 1.0000x reference)
//
#include <hip/hip_runtime.h>
#include <hip/hip_bf16.h>
#include <stdint.h>

#define L1DIM  1536
#define NOUT   144          // 128 (W1) + 16 (Wf) layer-1 outputs
#define NSPLIT 6            // K splits (B-sixth = 144*256*2B = 73728 B LDS)
#define KSPL   256          // K per split
#define KSTEPS 8            // K=32 MFMA steps per split
#define ROWS   16384
#define RT     16           // rows per tile
#define NRT    1024         // row tiles
#define BLKS   64           // blocks per split (grid = 384); 64*16 = 1024 exactly
#define PCOLS  32           // partial cols kept per row (bucket 16 + shared 16)

typedef __bf16 bf16;
typedef __bf16 bf16x8 __attribute__((ext_vector_type(8)));
typedef float  floatx4 __attribute__((ext_vector_type(4)));

// ---------------------------------------------------------------------------
// Pack [W1;Wf] (144 x 1536 fp32) -> bf16 in B-fragment order, grouped by
// K-sixth so each sixth is one contiguous 73728 B LDS image:
//   pw[(sixth*32 + o%32)*144 + n][0..7],  o = k/8 (k-octet 0..191)
// ---------------------------------------------------------------------------
__global__ void pack_weights(const float* __restrict__ W1,
                             const float* __restrict__ Wf,
                             bf16* __restrict__ pw) {
    int t = blockIdx.x * blockDim.x + threadIdx.x;   // 0 .. 144*192-1
    if (t >= NOUT * 192) return;
    int n = t / 192;         // output feature 0..143
    int o = t % 192;         // k-octet 0..191 (consecutive per lane -> coalesced)
    const float* src = (n < 128) ? (W1 + (size_t)n * L1DIM + o * 8)
                                 : (Wf + (size_t)(n - 128) * L1DIM + o * 8);
    float4 s0 = ((const float4*)src)[0];
    float4 s1 = ((const float4*)src)[1];
    bf16x8 v;
    v[0] = (bf16)s0.x; v[1] = (bf16)s0.y; v[2] = (bf16)s0.z; v[3] = (bf16)s0.w;
    v[4] = (bf16)s1.x; v[5] = (bf16)s1.y; v[6] = (bf16)s1.z; v[7] = (bf16)s1.w;
    int sixth = o >> 5, ol = o & 31;
    *(bf16x8*)(pw + (((size_t)sixth * 32 + ol) * NOUT + n) * 8) = v;
}

__device__ __forceinline__ void gload_lds16(const void* g, void* l) {
    __builtin_amdgcn_global_load_lds(
        (const __attribute__((address_space(1))) void*)g,
        (__attribute__((address_space(3))) void*)l, 16, 0, 0);
}

__device__ __forceinline__ bf16x8 cvt8(float4 a, float4 b) {
    bf16x8 r;
    r[0] = (bf16)a.x; r[1] = (bf16)a.y; r[2] = (bf16)a.z; r[3] = (bf16)a.w;
    r[4] = (bf16)b.x; r[5] = (bf16)b.y; r[6] = (bf16)b.z; r[7] = (bf16)b.w;
    return r;
}

// ---------------------------------------------------------------------------
// K-split layer-1 GEMM: grid = 6 splits x 64 blocks, 512 threads (8 waves).
// LDS = 73728 B -> 2 blocks/CU -> 16 waves/CU (4/SIMD) for latency hiding.
// Block stages its B-sixth into LDS ONCE (single barrier), then every wave
// free-runs a barrier-free K-loop over two independent 16-row tiles that
// share the B ds_reads. Bucket-gathered partials (32 cols/row) -> pt.
// ---------------------------------------------------------------------------
__global__ __launch_bounds__(512, 4) void gemm_l1(
    const float* __restrict__ x, const int* __restrict__ lsidx,
    const bf16* __restrict__ pw, float* __restrict__ pt)
{
    __shared__ bf16 lb[32 * NOUT * 8];   // 73728 B: one K-sixth of B

    const int tid  = threadIdx.x;
    const int wv   = tid >> 6;
    const int ln   = tid & 63;
    const int quad = ln >> 4;
    const int lm   = ln & 15;

    const int q   = blockIdx.x / BLKS;   // K-split id 0..5
    const int blk = blockIdx.x % BLKS;

    // ---- stage B-sixth (one barrier in the whole kernel) ----
    {
        const bf16* src = pw + (size_t)q * 32 * NOUT * 8;
        for (int c = tid; c < 32 * NOUT; c += 512)
            gload_lds16(src + (size_t)c * 8, &lb[(size_t)c * 8]);
    }
    __syncthreads();

    // ---- unit assignment: wave handles tiles tA and tB (all valid) ----
    const int tA = blk * 16 + wv;
    const int tB = blk * 16 + 8 + wv;
    const int rA = tA * RT;
    const int rB = tB * RT;

    const float* xa = x + (size_t)(rA + lm) * L1DIM + q * KSPL;
    const float* xb = x + (size_t)(rB + lm) * L1DIM + q * KSPL;

    floatx4 accA[9], accB[9];
#pragma unroll
    for (int i = 0; i < 9; i++) {
        accA[i] = (floatx4){0.f, 0.f, 0.f, 0.f};
        accB[i] = (floatx4){0.f, 0.f, 0.f, 0.f};
    }

    // ---- barrier-free K loop, A prefetched one step ahead ----
    float4 pa0 = *(const float4*)(xa + quad * 8);
    float4 pa1 = *(const float4*)(xa + quad * 8 + 4);
    float4 pb0 = *(const float4*)(xb + quad * 8);
    float4 pb1 = *(const float4*)(xb + quad * 8 + 4);

    for (int s = 0; s < KSTEPS; s++) {
        bf16x8 afA = cvt8(pa0, pa1);
        bf16x8 afB = cvt8(pb0, pb1);
        if (s < KSTEPS - 1) {
            const float* na = xa + (s + 1) * 32 + quad * 8;
            pa0 = *(const float4*)na;
            pa1 = *(const float4*)(na + 4);
            const float* nb = xb + (s + 1) * 32 + quad * 8;
            pb0 = *(const float4*)nb;
            pb1 = *(const float4*)(nb + 4);
        }
        const bf16* lbase = &lb[((size_t)(s * 4 + quad) * NOUT) * 8];
#pragma unroll
        for (int t = 0; t < 9; t++) {
            bf16x8 bfrag = *(const bf16x8*)&lbase[(t * 16 + lm) * 8];
            accA[t] = __builtin_amdgcn_mfma_f32_16x16x32_bf16(afA, bfrag, accA[t], 0, 0, 0);
            accB[t] = __builtin_amdgcn_mfma_f32_16x16x32_bf16(afB, bfrag, accB[t], 0, 0, 0);
        }
    }

    // ---- bucket-gather & store partials: pt[q][row][0..15]=bucket, [16..31]=shared ----
#pragma unroll
    for (int u = 0; u < 2; u++) {
        const floatx4* acc = u ? accB : accA;
        const int r0 = u ? rB : rA;
#pragma unroll
        for (int rp = 0; rp < 4; rp++) {
            const int row = r0 + quad * 4 + rp;
            const int bkt = lsidx[row];
            float c = acc[0][rp];
#pragma unroll
            for (int t = 1; t < 8; t++) c = (bkt == t) ? acc[t][rp] : c;
            const float f = acc[8][rp];
            float* dst = pt + ((size_t)q * ROWS + row) * PCOLS;
            dst[lm]      = c;
            dst[16 + lm] = f;
        }
    }
}

// ---------------------------------------------------------------------------
// Epilogue: sum the 6 K-split partials, add biases, layers 2+3.
// 256 threads = 32 rows x 8 threads.
// ---------------------------------------------------------------------------
__global__ __launch_bounds__(256) void epilogue(
    const float* __restrict__ pt, const int* __restrict__ lsidx,
    const float* __restrict__ b1, const float* __restrict__ bf_,
    const float* __restrict__ W2, const float* __restrict__ b2,
    const float* __restrict__ Wo, const float* __restrict__ bo,
    float* __restrict__ out)
{
    __shared__ float ep[32][33];

    const int tid = threadIdx.x;
    const int er  = tid >> 3;           // row in block, 0..31
    const int sub = tid & 7;            // 0..7
    const int row = blockIdx.x * 32 + er;

    // cooperative load: thread sums its float4 across the 6 splits
    float4 s = {0.f, 0.f, 0.f, 0.f};
#pragma unroll
    for (int q = 0; q < NSPLIT; q++) {
        float4 v = *(const float4*)&pt[((size_t)q * ROWS + row) * PCOLS + sub * 4];
        s.x += v.x; s.y += v.y; s.z += v.z; s.w += v.w;
    }
    *(float4*)&ep[er][sub * 4] = s;
    __syncthreads();

    const int bkt = lsidx[row];
    const float l1c15 = ep[er][15] + b1[bkt * 16 + 15];
    const float l1f15 = ep[er][31] + bf_[15];

    float l1x[30];
#pragma unroll
    for (int j = 0; j < 15; j++) {
        float tj = (ep[er][j] + b1[bkt * 16 + j]) + (ep[er][16 + j] + bf_[j]);
        float sq = tj * tj * (127.0f / 128.0f);
        l1x[j]      = fminf(fmaxf(sq, 0.f), 1.f);
        l1x[15 + j] = fminf(fmaxf(tj, 0.f), 1.f);
    }

    float part = 0.f;
#pragma unroll
    for (int o = 0; o < 8; o++) {
        const int oi = bkt * 64 + sub * 8 + o;
        const float2* wrow = (const float2*)(W2 + oi * 30);   // 8B-aligned
        float a = b2[oi];
#pragma unroll
        for (int j2 = 0; j2 < 15; j2++) {
            float2 w = wrow[j2];
            a += l1x[2 * j2] * w.x + l1x[2 * j2 + 1] * w.y;
        }
        a = fminf(fmaxf(a, 0.f), 1.f);
        part += a * Wo[oi];
    }
    part += __shfl_xor(part, 1);
    part += __shfl_xor(part, 2);
    part += __shfl_xor(part, 4);
    if (sub == 0) out[row] = part + bo[bkt] + l1c15 + l1f15;
}

extern "C" void kernel_launch(void* const* d_in, const int* in_sizes, int n_in,
                              void* d_out, int out_size, void* d_ws, size_t ws_size,
                              hipStream_t stream) {
    const float* x   = (const float*)d_in[0];
    const int*   idx = (const int*)  d_in[1];
    const float* W1  = (const float*)d_in[2];
    const float* b1  = (const float*)d_in[3];
    const float* Wf  = (const float*)d_in[4];
    const float* bf  = (const float*)d_in[5];
    const float* W2  = (const float*)d_in[6];
    const float* b2  = (const float*)d_in[7];
    const float* Wo  = (const float*)d_in[8];
    const float* bo  = (const float*)d_in[9];
    float* out = (float*)d_out;

    // ws layout: pt (6*16384*32*4 = 12.58 MB) | pw (442368 B)
    float* pt = (float*)d_ws;
    bf16*  pw = (bf16*)((char*)d_ws + (size_t)NSPLIT * ROWS * PCOLS * 4);

    pack_weights<<<dim3((NOUT * 192 + 255) / 256), dim3(256), 0, stream>>>(W1, Wf, pw);
    gemm_l1<<<dim3(NSPLIT * BLKS), dim3(512), 0, stream>>>(x, idx, pw, pt);
    epilogue<<<dim3(ROWS / 32), dim3(256), 0, stream>>>(pt, idx, b1, bf, W2, b2, Wo, bo, out);
}

// Round 6
// 192.580 us; speedup vs baseline: 1.0088x; 1.0088x over previous
//
#include <hip/hip_runtime.h>
#include <hip/hip_bf16.h>
#include <stdint.h>

#define L1DIM  1536
#define NOUT   144          // 128 (W1) + 16 (Wf) layer-1 outputs
#define NSPLIT 8            // K splits (B-eighth = 144*192*2B = 55296 B LDS)
#define KSPL   192          // K per split
#define KSTEPS 6            // K=32 MFMA steps per split
#define KOCT   24           // k-octets per split
#define ROWS   16384
#define RT     16           // rows per tile
#define NRT    1024         // row tiles
#define BLKS   64           // blocks per split; grid = 8*64 = 512 = 2/CU balanced
#define PCOLS  32           // partial cols kept per row (bucket 16 + shared 16)

typedef __bf16 bf16;
typedef __bf16 bf16x8 __attribute__((ext_vector_type(8)));
typedef float  floatx4 __attribute__((ext_vector_type(4)));

// ---------------------------------------------------------------------------
// Pack [W1;Wf] (144 x 1536 fp32) -> bf16 in B-fragment order, grouped by
// K-eighth so each eighth is one contiguous 55296 B LDS image:
//   pw[(split*24 + o%24)*144 + n][0..7],  o = k/8 (k-octet 0..191)
// ---------------------------------------------------------------------------
__global__ void pack_weights(const float* __restrict__ W1,
                             const float* __restrict__ Wf,
                             bf16* __restrict__ pw) {
    int t = blockIdx.x * blockDim.x + threadIdx.x;   // 0 .. 144*192-1
    if (t >= NOUT * 192) return;
    int n = t / 192;         // output feature 0..143
    int o = t % 192;         // k-octet 0..191 (consecutive per lane -> coalesced)
    const float* src = (n < 128) ? (W1 + (size_t)n * L1DIM + o * 8)
                                 : (Wf + (size_t)(n - 128) * L1DIM + o * 8);
    float4 s0 = ((const float4*)src)[0];
    float4 s1 = ((const float4*)src)[1];
    bf16x8 v;
    v[0] = (bf16)s0.x; v[1] = (bf16)s0.y; v[2] = (bf16)s0.z; v[3] = (bf16)s0.w;
    v[4] = (bf16)s1.x; v[5] = (bf16)s1.y; v[6] = (bf16)s1.z; v[7] = (bf16)s1.w;
    int spl = o / KOCT, ol = o % KOCT;
    *(bf16x8*)(pw + (((size_t)spl * KOCT + ol) * NOUT + n) * 8) = v;
}

__device__ __forceinline__ void gload_lds16(const void* g, void* l) {
    __builtin_amdgcn_global_load_lds(
        (const __attribute__((address_space(1))) void*)g,
        (__attribute__((address_space(3))) void*)l, 16, 0, 0);
}

__device__ __forceinline__ bf16x8 cvt8(float4 a, float4 b) {
    bf16x8 r;
    r[0] = (bf16)a.x; r[1] = (bf16)a.y; r[2] = (bf16)a.z; r[3] = (bf16)a.w;
    r[4] = (bf16)b.x; r[5] = (bf16)b.y; r[6] = (bf16)b.z; r[7] = (bf16)b.w;
    return r;
}

// ---------------------------------------------------------------------------
// K-split layer-1 GEMM: grid = 8 splits x 64 blocks = 512 (2/CU, BALANCED),
// 512 threads (8 waves). LDS 55296 B -> 2 blocks/CU -> 4 waves/SIMD.
// Block stages its B-eighth into LDS ONCE (single barrier), then every wave
// free-runs a barrier-free K-loop over two independent 16-row tiles that
// share the B ds_reads. Bucket-gathered partials (32 cols/row) -> pt.
// ---------------------------------------------------------------------------
__global__ __launch_bounds__(512, 4) void gemm_l1(
    const float* __restrict__ x, const int* __restrict__ lsidx,
    const bf16* __restrict__ pw, float* __restrict__ pt)
{
    __shared__ bf16 lb[KOCT * NOUT * 8];   // 55296 B: one K-eighth of B

    const int tid  = threadIdx.x;
    const int wv   = tid >> 6;
    const int ln   = tid & 63;
    const int quad = ln >> 4;
    const int lm   = ln & 15;

    const int q   = blockIdx.x >> 6;     // K-split id 0..7
    const int blk = blockIdx.x & 63;

    // ---- stage B-eighth (one barrier in the whole kernel) ----
    {
        const bf16* src = pw + (size_t)q * KOCT * NOUT * 8;
        for (int c = tid; c < KOCT * NOUT; c += 512)
            gload_lds16(src + (size_t)c * 8, &lb[(size_t)c * 8]);
    }
    __syncthreads();

    // ---- unit assignment: wave handles tiles tA and tB (all valid) ----
    const int rA = (blk * 16 + wv) * RT;
    const int rB = (blk * 16 + 8 + wv) * RT;

    const float* xa = x + (size_t)(rA + lm) * L1DIM + q * KSPL;
    const float* xb = x + (size_t)(rB + lm) * L1DIM + q * KSPL;

    floatx4 accA[9], accB[9];
#pragma unroll
    for (int i = 0; i < 9; i++) {
        accA[i] = (floatx4){0.f, 0.f, 0.f, 0.f};
        accB[i] = (floatx4){0.f, 0.f, 0.f, 0.f};
    }

    // ---- barrier-free K loop, A prefetched one step ahead ----
    float4 pa0 = *(const float4*)(xa + quad * 8);
    float4 pa1 = *(const float4*)(xa + quad * 8 + 4);
    float4 pb0 = *(const float4*)(xb + quad * 8);
    float4 pb1 = *(const float4*)(xb + quad * 8 + 4);

    for (int s = 0; s < KSTEPS; s++) {
        bf16x8 afA = cvt8(pa0, pa1);
        bf16x8 afB = cvt8(pb0, pb1);
        if (s < KSTEPS - 1) {
            const float* na = xa + (s + 1) * 32 + quad * 8;
            pa0 = *(const float4*)na;
            pa1 = *(const float4*)(na + 4);
            const float* nb = xb + (s + 1) * 32 + quad * 8;
            pb0 = *(const float4*)nb;
            pb1 = *(const float4*)(nb + 4);
        }
        const bf16* lbase = &lb[((size_t)(s * 4 + quad) * NOUT) * 8];
#pragma unroll
        for (int t = 0; t < 9; t++) {
            bf16x8 bfrag = *(const bf16x8*)&lbase[(t * 16 + lm) * 8];
            accA[t] = __builtin_amdgcn_mfma_f32_16x16x32_bf16(afA, bfrag, accA[t], 0, 0, 0);
            accB[t] = __builtin_amdgcn_mfma_f32_16x16x32_bf16(afB, bfrag, accB[t], 0, 0, 0);
        }
    }

    // ---- bucket-gather & store partials: pt[q][row][0..15]=bucket, [16..31]=shared ----
#pragma unroll
    for (int u = 0; u < 2; u++) {
        const floatx4* acc = u ? accB : accA;
        const int r0 = u ? rB : rA;
#pragma unroll
        for (int rp = 0; rp < 4; rp++) {
            const int row = r0 + quad * 4 + rp;
            const int bkt = lsidx[row];
            float c = acc[0][rp];
#pragma unroll
            for (int t = 1; t < 8; t++) c = (bkt == t) ? acc[t][rp] : c;
            const float f = acc[8][rp];
            float* dst = pt + ((size_t)q * ROWS + row) * PCOLS;
            dst[lm]      = c;
            dst[16 + lm] = f;
        }
    }
}

// ---------------------------------------------------------------------------
// Epilogue: sum the 8 K-split partials, add biases, layers 2+3.
// 256 threads = 32 rows x 8 threads.
// ---------------------------------------------------------------------------
__global__ __launch_bounds__(256) void epilogue(
    const float* __restrict__ pt, const int* __restrict__ lsidx,
    const float* __restrict__ b1, const float* __restrict__ bf_,
    const float* __restrict__ W2, const float* __restrict__ b2,
    const float* __restrict__ Wo, const float* __restrict__ bo,
    float* __restrict__ out)
{
    __shared__ float ep[32][33];

    const int tid = threadIdx.x;
    const int er  = tid >> 3;           // row in block, 0..31
    const int sub = tid & 7;            // 0..7
    const int row = blockIdx.x * 32 + er;

    // cooperative load: thread sums its float4 across the 8 splits
    float4 s = {0.f, 0.f, 0.f, 0.f};
#pragma unroll
    for (int q = 0; q < NSPLIT; q++) {
        float4 v = *(const float4*)&pt[((size_t)q * ROWS + row) * PCOLS + sub * 4];
        s.x += v.x; s.y += v.y; s.z += v.z; s.w += v.w;
    }
    *(float4*)&ep[er][sub * 4] = s;
    __syncthreads();

    const int bkt = lsidx[row];
    const float l1c15 = ep[er][15] + b1[bkt * 16 + 15];
    const float l1f15 = ep[er][31] + bf_[15];

    float l1x[30];
#pragma unroll
    for (int j = 0; j < 15; j++) {
        float tj = (ep[er][j] + b1[bkt * 16 + j]) + (ep[er][16 + j] + bf_[j]);
        float sq = tj * tj * (127.0f / 128.0f);
        l1x[j]      = fminf(fmaxf(sq, 0.f), 1.f);
        l1x[15 + j] = fminf(fmaxf(tj, 0.f), 1.f);
    }

    float part = 0.f;
#pragma unroll
    for (int o = 0; o < 8; o++) {
        const int oi = bkt * 64 + sub * 8 + o;
        const float2* wrow = (const float2*)(W2 + oi * 30);   // 8B-aligned
        float a = b2[oi];
#pragma unroll
        for (int j2 = 0; j2 < 15; j2++) {
            float2 w = wrow[j2];
            a += l1x[2 * j2] * w.x + l1x[2 * j2 + 1] * w.y;
        }
        a = fminf(fmaxf(a, 0.f), 1.f);
        part += a * Wo[oi];
    }
    part += __shfl_xor(part, 1);
    part += __shfl_xor(part, 2);
    part += __shfl_xor(part, 4);
    if (sub == 0) out[row] = part + bo[bkt] + l1c15 + l1f15;
}

extern "C" void kernel_launch(void* const* d_in, const int* in_sizes, int n_in,
                              void* d_out, int out_size, void* d_ws, size_t ws_size,
                              hipStream_t stream) {
    const float* x   = (const float*)d_in[0];
    const int*   idx = (const int*)  d_in[1];
    const float* W1  = (const float*)d_in[2];
    const float* b1  = (const float*)d_in[3];
    const float* Wf  = (const float*)d_in[4];
    const float* bf  = (const float*)d_in[5];
    const float* W2  = (const float*)d_in[6];
    const float* b2  = (const float*)d_in[7];
    const float* Wo  = (const float*)d_in[8];
    const float* bo  = (const float*)d_in[9];
    float* out = (float*)d_out;

    // ws layout: pt (8*16384*32*4 = 16.78 MB) | pw (442368 B)
    float* pt = (float*)d_ws;
    bf16*  pw = (bf16*)((char*)d_ws + (size_t)NSPLIT * ROWS * PCOLS * 4);

    pack_weights<<<dim3((NOUT * 192 + 255) / 256), dim3(256), 0, stream>>>(W1, Wf, pw);
    gemm_l1<<<dim3(NSPLIT * BLKS), dim3(512), 0, stream>>>(x, idx, pw, pt);
    epilogue<<<dim3(ROWS / 32), dim3(256), 0, stream>>>(pt, idx, b1, bf, W2, b2, Wo, bo, out);
}

// Round 7
// 179.879 us; speedup vs baseline: 1.0800x; 1.0706x over previous
//
#include <hip/hip_runtime.h>
#include <hip/hip_bf16.h>
#include <stdint.h>

#define L1DIM 1536
#define NOUT  144           // 128 (W1) + 16 (Wf) layer-1 outputs
#define MTILE 32            // rows per block
#define BK    64            // K per staged slab
#define NITER (L1DIM / BK)  // 24
#define BCH   18            // B slab 1-KB chunks (8 k-oct * 144 * 16B = 18432 B)

typedef __bf16 bf16;
typedef __bf16 bf16x8 __attribute__((ext_vector_type(8)));
typedef float  floatx4 __attribute__((ext_vector_type(4)));

// ---------------------------------------------------------------------------
// Pack [W1;Wf] (144 x 1536 fp32) -> bf16 in MFMA B-fragment order:
//   pw[(k/8)*144 + n][0..7]  (16 B per (k-octet, feature)); one BK=64 slab
//   = 18432 B contiguous. Reads coalesced (consecutive lanes, consecutive o).
// ---------------------------------------------------------------------------
__global__ void pack_weights(const float* __restrict__ W1,
                             const float* __restrict__ Wf,
                             bf16* __restrict__ pw) {
    int t = blockIdx.x * blockDim.x + threadIdx.x;   // 0 .. 144*192-1
    if (t >= NOUT * 192) return;
    int n = t / 192;         // output feature 0..143
    int o = t % 192;         // k-octet 0..191
    const float* src = (n < 128) ? (W1 + (size_t)n * L1DIM + o * 8)
                                 : (Wf + (size_t)(n - 128) * L1DIM + o * 8);
    float4 s0 = ((const float4*)src)[0];
    float4 s1 = ((const float4*)src)[1];
    bf16x8 v;
    v[0] = (bf16)s0.x; v[1] = (bf16)s0.y; v[2] = (bf16)s0.z; v[3] = (bf16)s0.w;
    v[4] = (bf16)s1.x; v[5] = (bf16)s1.y; v[6] = (bf16)s1.z; v[7] = (bf16)s1.w;
    *(bf16x8*)(pw + ((size_t)o * NOUT + n) * 8) = v;
}

__device__ __forceinline__ void gload_lds16(const void* g, void* l) {
    __builtin_amdgcn_global_load_lds(
        (const __attribute__((address_space(1))) void*)g,
        (__attribute__((address_space(3))) void*)l, 16, 0, 0);
}

__device__ __forceinline__ bf16x8 cvt8(float4 a, float4 b) {
    bf16x8 r;
    r[0] = (bf16)a.x; r[1] = (bf16)a.y; r[2] = (bf16)a.z; r[3] = (bf16)a.w;
    r[4] = (bf16)b.x; r[5] = (bf16)b.y; r[6] = (bf16)b.z; r[7] = (bf16)b.w;
    return r;
}

// ---------------------------------------------------------------------------
// Fused kernel, m97-style double-buffered K-loop. 256 threads = 4 waves:
// wave = (m-half ms) x (n-half nh). Grid 512 = 2 blocks/CU, balanced.
// BOTH operands staged wave-contiguously via global_load_lds width-16:
//   A: x rows R0..R0+31, BK floats/row fp32; instruction j covers rows
//      4j..4j+3 as 4 contiguous 256-B spans. 16-B chunk c of row r is stored
//      at LDS slot (c ^ (r&7)) via permuting the GLOBAL fetch, so the
//      256-B row stride doesn't produce ds_read bank conflicts.
//   B: packed bf16 slab, 18 contiguous 1-KB chunks.
// One barrier per iter; stage(k+1) issued before compute(k) so the pre-barrier
// vmcnt(0) drain overlaps compute.
// ---------------------------------------------------------------------------
__global__ __launch_bounds__(256, 2) void layerstacks_main(
    const float* __restrict__ x, const int* __restrict__ lsidx,
    const bf16* __restrict__ pw,
    const float* __restrict__ b1, const float* __restrict__ bf_,
    const float* __restrict__ W2, const float* __restrict__ b2,
    const float* __restrict__ Wo, const float* __restrict__ bo,
    float* __restrict__ out)
{
    __shared__ float la[2][MTILE * BK];      // 2 x 8192 B   (A, fp32, swizzled)
    __shared__ bf16  lb[2][8 * NOUT * 8];    // 2 x 18432 B  (B, fragment order)
    __shared__ float ep[MTILE][33];          // layer-1 results

    const int tid  = threadIdx.x;
    const int wv   = tid >> 6;
    const int ln   = tid & 63;
    const int quad = ln >> 4;
    const int lm   = ln & 15;

    const int R0  = blockIdx.x * MTILE;
    const int ms  = wv & 1;                 // m half (16 rows)
    const int nh  = wv >> 1;                // n half
    const int nt0 = nh ? 5 : 0;
    const int ntn = nh ? 4 : 5;

    // ---- A staging lane geometry (fixed per lane) ----
    // instr j: rows 4j..4j+3; lane i -> row 4j + (i>>4), lds slot i&15,
    // global chunk (i&15) ^ (row&7)  [swizzle folded into global fetch]
    const int sr  = ln >> 4;                // row-within-group 0..3
    const int sch = ln & 15;                // lds slot 0..15

    floatx4 acc[5];
#pragma unroll
    for (int i = 0; i < 5; i++) acc[i] = (floatx4){0.f, 0.f, 0.f, 0.f};

    // ---- stage helper (emitted twice: prologue + in-loop) ----
    // A: 8 instrs, wave wv does j = 2*wv, 2*wv+1
    // B: 18 instrs, wave wv does c = wv, wv+4, ...
#define STAGE(buf, ki_)                                                          \
    {                                                                            \
        const int k0_ = (ki_) * BK;                                              \
        _Pragma("unroll")                                                        \
        for (int jj = 0; jj < 2; jj++) {                                         \
            const int j    = 2 * wv + jj;                                        \
            const int row  = 4 * j + sr;                                         \
            const int cg   = sch ^ (row & 7);                                    \
            gload_lds16(x + (size_t)(R0 + row) * L1DIM + k0_ + cg * 4,           \
                        &la[buf][j * 4 * BK + sr * BK + sch * 4]);               \
        }                                                                        \
        const bf16* bsrc_ = pw + (size_t)(ki_) * 8 * NOUT * 8;                   \
        _Pragma("unroll")                                                        \
        for (int cc = wv; cc < BCH; cc += 4) {                                   \
            gload_lds16(bsrc_ + (size_t)cc * 512 + ln * 8,                       \
                        &lb[buf][(size_t)cc * 512 + ln * 8]);                    \
        }                                                                        \
    }

    STAGE(0, 0)
    __syncthreads();

    for (int ki = 0; ki < NITER; ki++) {
        const int cur = ki & 1;
        if (ki < NITER - 1) STAGE(cur ^ 1, ki + 1)

        // ---- compute on current slab ----
#pragma unroll
        for (int s = 0; s < 2; s++) {
            // A-frag: row = ms*16+lm, k = s*32 + quad*8 (chunks c0, c0+1)
            const int row = ms * 16 + lm;
            const int c0  = s * 8 + quad * 2;
            float4 a0 = *(const float4*)&la[cur][row * BK + ((c0)     ^ (row & 7)) * 4];
            float4 a1 = *(const float4*)&la[cur][row * BK + ((c0 + 1) ^ (row & 7)) * 4];
            bf16x8 af = cvt8(a0, a1);
            const bf16* bbase = &lb[cur][((size_t)(s * 4 + quad) * NOUT) * 8];
#pragma unroll
            for (int t = 0; t < 5; t++) {
                if (t < ntn) {
                    bf16x8 bfrag = *(const bf16x8*)&bbase[((nt0 + t) * 16 + lm) * 8];
                    acc[t] = __builtin_amdgcn_mfma_f32_16x16x32_bf16(af, bfrag, acc[t], 0, 0, 0);
                }
            }
        }
        __syncthreads();   // drains next-slab staging; frees cur for overwrite
    }

    // ---- bucket-gather layer-1 results to ep (C layout: row=quad*4+r, col=lm) ----
    // ep[row][0..15] = selected-bucket cols, ep[row][16..31] = shared (Wf) cols
    {
        const int rbase = ms * 16 + quad * 4;
#pragma unroll
        for (int r = 0; r < 4; r++) {
            const int row = rbase + r;
            const int bkt = lsidx[R0 + row];
            if (nh == 0) {
                // tiles 0..4 hold buckets 0..4 (cols bkt*16) -- tile 8 is Wf half
                float c = acc[0][r];
#pragma unroll
                for (int t = 1; t < 5; t++) c = (bkt == t) ? acc[t][r] : c;
                if (bkt < 5) ep[row][lm] = c;
            } else {
                // tiles 5..7 = buckets 5..7, tile 8 = Wf
                float c = acc[0][r];
                c = (bkt == 6) ? acc[1][r] : c;
                c = (bkt == 7) ? acc[2][r] : c;
                if (bkt >= 5) ep[row][lm] = c;
                ep[row][16 + lm] = acc[3][r];
            }
        }
    }
    __syncthreads();

    // ---- epilogue: 8 threads per row, 32 rows ----
    const int er   = tid >> 3;          // row in tile, 0..31
    const int sub  = tid & 7;           // output-group, 0..7
    const int grow = R0 + er;
    const int bkt  = lsidx[grow];

    const float l1c15 = ep[er][15] + b1[bkt * 16 + 15];
    const float l1f15 = ep[er][31] + bf_[15];

    float l1x[30];
#pragma unroll
    for (int j = 0; j < 15; j++) {
        float tj = (ep[er][j] + b1[bkt * 16 + j]) + (ep[er][16 + j] + bf_[j]);
        float sq = tj * tj * (127.0f / 128.0f);
        l1x[j]      = fminf(fmaxf(sq, 0.f), 1.f);
        l1x[15 + j] = fminf(fmaxf(tj, 0.f), 1.f);
    }

    float part = 0.f;
#pragma unroll
    for (int o = 0; o < 8; o++) {
        const int oi = bkt * 64 + sub * 8 + o;
        const float2* wrow = (const float2*)(W2 + oi * 30);   // 8B-aligned
        float a = b2[oi];
#pragma unroll
        for (int j2 = 0; j2 < 15; j2++) {
            float2 w = wrow[j2];
            a += l1x[2 * j2] * w.x + l1x[2 * j2 + 1] * w.y;
        }
        a = fminf(fmaxf(a, 0.f), 1.f);
        part += a * Wo[oi];
    }
    part += __shfl_xor(part, 1);
    part += __shfl_xor(part, 2);
    part += __shfl_xor(part, 4);
    if (sub == 0) out[grow] = part + bo[bkt] + l1c15 + l1f15;
}

extern "C" void kernel_launch(void* const* d_in, const int* in_sizes, int n_in,
                              void* d_out, int out_size, void* d_ws, size_t ws_size,
                              hipStream_t stream) {
    const float* x   = (const float*)d_in[0];
    const int*   idx = (const int*)  d_in[1];
    const float* W1  = (const float*)d_in[2];
    const float* b1  = (const float*)d_in[3];
    const float* Wf  = (const float*)d_in[4];
    const float* bf  = (const float*)d_in[5];
    const float* W2  = (const float*)d_in[6];
    const float* b2  = (const float*)d_in[7];
    const float* Wo  = (const float*)d_in[8];
    const float* bo  = (const float*)d_in[9];
    float* out = (float*)d_out;
    bf16*  pw  = (bf16*)d_ws;                 // 442368 B of workspace

    pack_weights<<<dim3((NOUT * 192 + 255) / 256), dim3(256), 0, stream>>>(W1, Wf, pw);
    layerstacks_main<<<dim3(16384 / MTILE), dim3(256), 0, stream>>>(
        x, idx, pw, b1, bf, W2, b2, Wo, bo, out);
}